// Round 16
// baseline (223.644 us; speedup 1.0000x reference)
//
#include <hip/hip_runtime.h>
#include <hip/hip_bf16.h>
#include <stdint.h>

#define S_LEN 2048
#define NH 16
#define HD 64
#define DM 1024
#define DFF 4096
#define MTOK 4096   // B*S = 2*2048

typedef __attribute__((ext_vector_type(8))) short short8;
typedef __attribute__((ext_vector_type(4))) float f32x4;
typedef __attribute__((ext_vector_type(16))) float f32x16;
typedef __attribute__((ext_vector_type(2))) int i32x2;
typedef unsigned short u16;
typedef unsigned int u32;

__device__ __forceinline__ float bf2f(u16 u) {
  union { u32 i; float f; } x; x.i = ((u32)u) << 16; return x.f;
}
__device__ __forceinline__ u16 f2bf(float f) {
  union { float f; u32 i; } x; x.f = f;
  u32 r = x.i + 0x7fffu + ((x.i >> 16) & 1u);
  return (u16)(r >> 16);
}
// Schraudolph fast exp2 (full-rate fma+cvt; softmax normalization cancels bias)
__device__ __forceinline__ float exp2_fast(float x) {
  union { int i; float f; } u;
  u.i = (int)__builtin_fmaf(x, 8388608.0f, 1064986823.0f);
  return u.f;
}
__device__ __forceinline__ void gload16(const u16* g, u16* l) {
  __builtin_amdgcn_global_load_lds(
      (__attribute__((address_space(1))) u32*)g,
      (__attribute__((address_space(3))) u32*)l, 16, 0, 0);
}

#define VM0 asm volatile("s_waitcnt vmcnt(0)" ::: "memory")
#define VM6 asm volatile("s_waitcnt vmcnt(6)" ::: "memory")
#define BARR do { __builtin_amdgcn_s_barrier(); asm volatile("" ::: "memory"); } while (0)
#define LGKM0 do { asm volatile("s_waitcnt lgkmcnt(0)" ::: "memory"); __builtin_amdgcn_sched_barrier(0); } while (0)
#define PRIO1 __builtin_amdgcn_s_setprio(1)
#define PRIO0 __builtin_amdgcn_s_setprio(0)

// ---------- fused prep: 6 weight transposes + RoPE table + LN1, one launch ----------
__device__ __forceinline__ void transpose_tile(const float* __restrict__ W,
                                               u16* __restrict__ Wt, int K, int N,
                                               int n0, int k0, int tx, int ty,
                                               float (*tile)[33]) {
#pragma unroll
  for (int i = 0; i < 4; ++i)
    tile[ty + i * 8][tx] = W[(size_t)(k0 + ty + i * 8) * N + n0 + tx];
  __syncthreads();
#pragma unroll
  for (int i = 0; i < 4; ++i)
    Wt[(size_t)(n0 + ty + i * 8) * K + k0 + tx] = f2bf(tile[tx][ty + i * 8]);
}

__global__ __launch_bounds__(256) void prep(
    const float* __restrict__ Wq, const float* __restrict__ Wk,
    const float* __restrict__ Wv, const float* __restrict__ Wo,
    const float* __restrict__ W1, const float* __restrict__ W2,
    u16* __restrict__ WQKVT, u16* __restrict__ WOT, u16* __restrict__ W1T,
    u16* __restrict__ W2T, float* __restrict__ cosT, float* __restrict__ sinT,
    const float* __restrict__ x, const float* __restrict__ g,
    const float* __restrict__ b, u16* __restrict__ H) {
  __shared__ float tile[32][33];
  __shared__ float red[8];
  const int r = blockIdx.x;
  const int t = threadIdx.x;
  const int tx = t & 31, ty = t >> 5;
  if (r < 4096) {
    const float* W = (r < 1024) ? Wq : (r < 2048) ? Wk : (r < 3072) ? Wv : Wo;
    u16* Wt = (r < 1024) ? WQKVT
              : (r < 2048) ? WQKVT + 1024 * 1024
              : (r < 3072) ? WQKVT + 2 * 1024 * 1024 : WOT;
    int sub = r & 1023;
    transpose_tile(W, Wt, 1024, 1024, (sub & 31) * 32, (sub >> 5) * 32, tx, ty, tile);
  } else if (r < 8192) {
    int sub = r - 4096;  // W1: K=1024, N=4096
    transpose_tile(W1, W1T, 1024, 4096, (sub & 127) * 32, (sub >> 7) * 32, tx, ty, tile);
  } else if (r < 12288) {
    int sub = r - 8192;  // W2: K=4096, N=1024
    transpose_tile(W2, W2T, 4096, 1024, (sub & 31) * 32, (sub >> 5) * 32, tx, ty, tile);
  } else if (r < 12544) {
    int id = (r - 12288) * 256 + t;  // 2048*32
    int s = id >> 5, j = id & 31;
    float inv = powf(10000.0f, -(float)j * (1.0f / 32.0f));
    float fr = (float)s * inv;
    cosT[id] = cosf(fr);
    sinT[id] = sinf(fr);
  } else {
    // LN1 row
    int row = r - 12544;
    float4 v = ((const float4*)(x + ((size_t)row << 10)))[t];
    float s = v.x + v.y + v.z + v.w;
    float q = v.x * v.x + v.y * v.y + v.z * v.z + v.w * v.w;
#pragma unroll
    for (int m = 1; m < 64; m <<= 1) {
      s += __shfl_xor(s, m, 64);
      q += __shfl_xor(q, m, 64);
    }
    int lane = t & 63, w = t >> 6;
    if (lane == 0) { red[w] = s; red[4 + w] = q; }
    __syncthreads();
    s = red[0] + red[1] + red[2] + red[3];
    q = red[4] + red[5] + red[6] + red[7];
    float mu = s * (1.0f / 1024.0f);
    float var = q * (1.0f / 1024.0f) - mu * mu;
    float rstd = rsqrtf(var + 1e-5f);
    float4 gv = ((const float4*)g)[t];
    float4 bv = ((const float4*)b)[t];
    ushort4 o;
    o.x = f2bf((v.x - mu) * rstd * gv.x + bv.x);
    o.y = f2bf((v.y - mu) * rstd * gv.y + bv.y);
    o.z = f2bf((v.z - mu) * rstd * gv.z + bv.z);
    o.w = f2bf((v.w - mu) * rstd * gv.w + bv.w);
    ((ushort4*)(H + ((size_t)row << 10)))[t] = o;
  }
}

// ---------- LayerNorm fp32 row(1024) -> bf16 (LN2) ----------
__global__ __launch_bounds__(256) void ln_bf16(const float* __restrict__ x,
                                               const float* __restrict__ g,
                                               const float* __restrict__ b,
                                               u16* __restrict__ out) {
  int row = blockIdx.x;
  int t = threadIdx.x;
  float4 v = ((const float4*)(x + ((size_t)row << 10)))[t];
  float s = v.x + v.y + v.z + v.w;
  float q = v.x * v.x + v.y * v.y + v.z * v.z + v.w * v.w;
#pragma unroll
  for (int m = 1; m < 64; m <<= 1) {
    s += __shfl_xor(s, m, 64);
    q += __shfl_xor(q, m, 64);
  }
  __shared__ float red[8];
  int lane = t & 63, w = t >> 6;
  if (lane == 0) { red[w] = s; red[4 + w] = q; }
  __syncthreads();
  s = red[0] + red[1] + red[2] + red[3];
  q = red[4] + red[5] + red[6] + red[7];
  float mu = s * (1.0f / 1024.0f);
  float var = q * (1.0f / 1024.0f) - mu * mu;
  float rstd = rsqrtf(var + 1e-5f);
  float4 gv = ((const float4*)g)[t];
  float4 bv = ((const float4*)b)[t];
  ushort4 o;
  o.x = f2bf((v.x - mu) * rstd * gv.x + bv.x);
  o.y = f2bf((v.y - mu) * rstd * gv.y + bv.y);
  o.z = f2bf((v.z - mu) * rstd * gv.z + bv.z);
  o.w = f2bf((v.w - mu) * rstd * gv.w + bv.w);
  ((ushort4*)(out + ((size_t)row << 10)))[t] = o;
}

// ---------- 256x256 GEMM, m201-faithful: quarter staging, dual barrier/phase, ----------
// tile-end vmcnt+barrier (drain-then-publish). 8 waves (2Mx4N), per-wave 128x64.
// Phase reads: P1 a[0..3]+b[0..1] (12 b128), P2 b[2..3] (4), P3 a[4..7] (8), P4 none.
// Staging (1 load/thr/quarter): P1 BQ2,3(t+1)->s^1; P2 AQ0,AQ2(t+2)->s;
// P3 BQ0,BQ1(t+2)->s; P4 AQ1,AQ3(t+2)->s. In-flight after tile-end vmcnt(6): 6.
#define MMQ4(IB, NB)                                                         \
  _Pragma("unroll") for (int i_ = 0; i_ < 4; ++i_)                           \
  _Pragma("unroll") for (int n_ = 0; n_ < 2; ++n_)                           \
  _Pragma("unroll") for (int k_ = 0; k_ < 2; ++k_)                           \
    acc[(IB) + i_][(NB) + n_] = __builtin_amdgcn_mfma_f32_16x16x32_bf16(     \
        a[i_][k_], b[(NB) + n_][k_], acc[(IB) + i_][(NB) + n_], 0, 0, 0);

template <int EPI>
__global__ __launch_bounds__(512, 1) void gemm256(
    const u16* __restrict__ A, const u16* __restrict__ Bt, int N, int K,
    const float* __restrict__ bias, const float* __restrict__ bq,
    const float* __restrict__ bk, const float* __restrict__ bv,
    const float* __restrict__ cosT, const float* __restrict__ sinT,
    u16* __restrict__ d0, u16* __restrict__ d1, u16* __restrict__ d2) {
  __shared__ __align__(16) u16 As[2][256 * 64];
  __shared__ __align__(16) u16 Bs[2][256 * 64];
  const int t = threadIdx.x;
  const int lane = t & 63, wid = t >> 6;
  const int fr = lane & 15, fq = lane >> 4;
  const int m0 = blockIdx.y << 8, n0 = blockIdx.x << 8;
  const int wmo = (wid >> 2) << 7;   // 0/128
  const int wno = (wid & 3) << 6;    // 0..192
  const int r7 = fr & 7;
  const int ssl = t & 7;
  const u16* Ap = A + (size_t)m0 * K;
  const u16* Bp = Bt + (size_t)n0 * K;

  f32x4 acc[8][4];
#pragma unroll
  for (int i = 0; i < 8; ++i)
#pragma unroll
    for (int n = 0; n < 4; ++n) acc[i][n] = (f32x4){0.f, 0.f, 0.f, 0.f};

  short8 a[4][2], b[4][2];

  // stage one 64-row quarter: 1 load/thread
  auto stageQ = [&](u16* dstSlot, const u16* src, int rowOff, int kt) {
    const int R = rowOff + (t >> 3);
    gload16(src + (size_t)R * K + kt + ((ssl ^ (R & 7)) << 3),
            dstSlot + (size_t)R * 64 + ssl * 8);
  };
  auto readA4 = [&](int slot, int ibase) {  // 4 A-frags into a[0..3]
#pragma unroll
    for (int i = 0; i < 4; ++i) {
      const u16* rp = &As[slot][(wmo + ((ibase + i) << 4) + fr) << 6];
      a[i][0] = *(const short8*)(rp + ((fq ^ r7) << 3));
      a[i][1] = *(const short8*)(rp + (((4 + fq) ^ r7) << 3));
    }
  };
  auto readB2 = [&](int slot, int nbase) {
#pragma unroll
    for (int n = 0; n < 2; ++n) {
      const u16* rp = &Bs[slot][(wno + ((nbase + n) << 4) + fr) << 6];
      b[nbase + n][0] = *(const short8*)(rp + ((fq ^ r7) << 3));
      b[nbase + n][1] = *(const short8*)(rp + (((4 + fq) ^ r7) << 3));
    }
  };

  const int nt = K >> 6;
  // prologue: tile0 all 8 quarters FIRST (drained by VM6 below), then tile1's 6
  stageQ(&As[0][0], Ap, 0, 0);   stageQ(&As[0][0], Ap, 64, 0);
  stageQ(&As[0][0], Ap, 128, 0); stageQ(&As[0][0], Ap, 192, 0);
  stageQ(&Bs[0][0], Bp, 0, 0);   stageQ(&Bs[0][0], Bp, 64, 0);
  stageQ(&Bs[0][0], Bp, 128, 0); stageQ(&Bs[0][0], Bp, 192, 0);
  stageQ(&As[1][0], Ap, 0, 64);  stageQ(&As[1][0], Ap, 128, 64);
  stageQ(&Bs[1][0], Bp, 0, 64);  stageQ(&Bs[1][0], Bp, 64, 64);
  stageQ(&As[1][0], Ap, 64, 64); stageQ(&As[1][0], Ap, 192, 64);
  if (nt > 1) { VM6; } else { VM0; }  // tile0's 8 drained; tile1's 6 in flight
  BARR;                                // publish

  for (int tt = 0; tt < nt; ++tt) {
    const int s = tt & 1;
    u16* Asl = &As[s][0];
    u16* Bsl = &Bs[s][0];
    u16* Bnx = &Bs[s ^ 1][0];
    const int kt1 = (tt + 1) << 6, kt2 = (tt + 2) << 6;
    const bool st1 = (tt + 1 < nt), st2 = (tt + 2 < nt);
    // P1
    readA4(s, 0); readB2(s, 0);
    if (st1) { stageQ(Bnx, Bp, 128, kt1); stageQ(Bnx, Bp, 192, kt1); }
    BARR; LGKM0;
    PRIO1; MMQ4(0, 0); PRIO0;
    BARR;
    // P2
    readB2(s, 2);
    if (st2) { stageQ(Asl, Ap, 0, kt2); stageQ(Asl, Ap, 128, kt2); }
    BARR; LGKM0;
    PRIO1; MMQ4(0, 2); PRIO0;
    BARR;
    // P3
    readA4(s, 4);
    if (st2) { stageQ(Bsl, Bp, 0, kt2); stageQ(Bsl, Bp, 64, kt2); }
    BARR; LGKM0;
    PRIO1; MMQ4(4, 2); PRIO0;
    BARR;
    // P4
    if (st2) { stageQ(Asl, Ap, 64, kt2); stageQ(Asl, Ap, 192, kt2); }
    BARR;
    PRIO1; MMQ4(4, 0); PRIO0;
    if (st2) { VM6; } else { VM0; }  // drain tile t+1 fully; keep t+2's 6 in flight
    BARR;                             // publish tile t+1 to all waves
  }

  if (EPI == 0) {
    const int colbase = n0 + wno;
    const int slice = colbase >> 10;  // 0=Q 1=K 2=V
    const int cb = colbase & 1023;
    const int hh = cb >> 6;
    if (slice < 2) {
      const float sc = (slice == 0) ? 0.125f * 1.44269504088896f : 1.0f;
      const float* bb_ = (slice == 0) ? bq : bk;
      u16* dst = (slice == 0) ? d0 : d1;
#pragma unroll
      for (int i = 0; i < 8; ++i) {
        const int row0 = m0 + wmo + (i << 4) + (fq << 2);
#pragma unroll
        for (int n = 0; n < 2; ++n) {
          const int d = n * 16 + fr;
          const float blo = bb_[cb + d];
          const float bhi = bb_[cb + d + 32];
#pragma unroll
          for (int j = 0; j < 4; ++j) {
            const int row = row0 + j;
            const int ss = row & 2047, bb2 = row >> 11;
            const float c = cosT[ss * 32 + d];
            const float sn = sinT[ss * 32 + d];
            const float av = acc[i][n][j] + blo;
            const float bv2 = acc[i][n + 2][j] + bhi;
            const size_t base = ((size_t)((bb2 * 16 + hh) * 2048 + ss)) << 6;
            dst[base + d] = f2bf((av * c - bv2 * sn) * sc);
            dst[base + d + 32] = f2bf((bv2 * c + av * sn) * sc);
          }
        }
      }
    } else {
#pragma unroll
      for (int i = 0; i < 8; ++i) {
        const int row0 = m0 + wmo + (i << 4) + (fq << 2);
#pragma unroll
        for (int n = 0; n < 4; ++n) {
          const int d = n * 16 + fr;
          const float bia = bv[cb + d];
#pragma unroll
          for (int j = 0; j < 4; ++j) {
            const int row = row0 + j;
            const int ss = row & 2047, bb2 = row >> 11;
            d2[((size_t)((bb2 * 16 + hh) * 64 + d)) * 2048 + ss] =
                f2bf(acc[i][n][j] + bia);
          }
        }
      }
    }
  } else {
#pragma unroll
    for (int i = 0; i < 8; ++i) {
      const int row0 = m0 + wmo + (i << 4) + (fq << 2);
#pragma unroll
      for (int n = 0; n < 4; ++n) {
        const int col = n0 + wno + n * 16 + fr;
        const float bia = bias[col];
#pragma unroll
        for (int j = 0; j < 4; ++j) {
          const int row = row0 + j;
          const float v = acc[i][n][j] + bia;
          const float gl = 0.5f * v * (1.0f + erff(v * 0.70710678118f));
          d0[(size_t)row * N + col] = f2bf(gl);
        }
      }
    }
  }
}

// ---------- N=1024 GEMM (Wo, FFN2): 128x128 tile, intra-block split-K ----------
__global__ __launch_bounds__(512, 1) void gemm_split(
    const u16* __restrict__ A, const u16* __restrict__ Bt, int K,
    const float* __restrict__ bias, const float* __restrict__ resid,
    float* __restrict__ dst) {
  __shared__ __align__(16) u16 As[2][128 * 128];
  __shared__ __align__(16) u16 Bs[2][128 * 128];
  const int t = threadIdx.x, lane = t & 63, w = t >> 6;  // 8 waves
  const int fr = lane & 15, fq = lane >> 4;
  const int wq = w & 3, kh = w >> 2;
  const int wm = (wq >> 1) << 6, wn = (wq & 1) << 6;
  const int bid = blockIdx.x;
  const int xcd = bid & 7, within = bid >> 3;            // 32 blocks/XCD
  const int m0 = (xcd * 4 + (within >> 3)) << 7;         // 32 m-tiles
  const int n0 = (within & 7) << 7;                      // 8 n-tiles
  const int srow = t >> 4;   // 0..31
  const int ssl = t & 15;    // 16B slot 0..15

  f32x4 acc[4][4];
#pragma unroll
  for (int i = 0; i < 4; ++i)
#pragma unroll
    for (int n = 0; n < 4; ++n) acc[i][n] = (f32x4){0.f, 0.f, 0.f, 0.f};

  auto stage = [&](int buf, int kt) {
#pragma unroll
    for (int c = 0; c < 4; ++c) {
      const int R = c * 32 + srow;
      const int gs = ssl ^ (R & 15);
      gload16(A + (size_t)(m0 + R) * K + kt + gs * 8, &As[buf][R * 128 + ssl * 8]);
    }
#pragma unroll
    for (int c = 0; c < 4; ++c) {
      const int R = c * 32 + srow;
      const int gs = ssl ^ (R & 15);
      gload16(Bt + (size_t)(n0 + R) * K + kt + gs * 8, &Bs[buf][R * 128 + ssl * 8]);
    }
  };

  stage(0, 0);
  int buf = 0;
  const int iters = K >> 7;
  for (int it = 0; it < iters; ++it) {
    VM0;
    BARR;
    if (it + 1 < iters) stage(buf ^ 1, (it + 1) << 7);

    short8 a[4][2], b[4][2];
#pragma unroll
    for (int i = 0; i < 4; ++i) {
      const u16* rp = &As[buf][(wm + i * 16 + fr) * 128];
#pragma unroll
      for (int ks = 0; ks < 2; ++ks)
        a[i][ks] = *(const short8*)(rp + (((kh * 8 + ks * 4 + fq) ^ fr) << 3));
    }
#pragma unroll
    for (int n = 0; n < 4; ++n) {
      const u16* rp = &Bs[buf][(wn + n * 16 + fr) * 128];
#pragma unroll
      for (int ks = 0; ks < 2; ++ks)
        b[n][ks] = *(const short8*)(rp + (((kh * 8 + ks * 4 + fq) ^ fr) << 3));
    }
    PRIO1;
#pragma unroll
    for (int i = 0; i < 4; ++i)
#pragma unroll
      for (int n = 0; n < 4; ++n)
#pragma unroll
        for (int ks = 0; ks < 2; ++ks)
          acc[i][n] = __builtin_amdgcn_mfma_f32_16x16x32_bf16(a[i][ks], b[n][ks],
                                                              acc[i][n], 0, 0, 0);
    PRIO0;
    buf ^= 1;
  }

  // ---- k-half merge via LDS: [wq][col 0..63][row 0..63 pad->68] f32
  BARR;
  float* mrg = (float*)&As[0][0];
  if (kh == 1) {
#pragma unroll
    for (int i = 0; i < 4; ++i) {
      const int ri = i * 16 + (fq << 2);
#pragma unroll
      for (int n = 0; n < 4; ++n) {
        const int ci = n * 16 + fr;
        *(f32x4*)(mrg + wq * 4352 + ci * 68 + ri) = acc[i][n];
      }
    }
  }
  LGKM0;
  BARR;
  if (kh == 0) {
#pragma unroll
    for (int i = 0; i < 4; ++i) {
      const int ri = i * 16 + (fq << 2);
      const int row0 = m0 + wm + ri;
#pragma unroll
      for (int n = 0; n < 4; ++n) {
        const int ci = n * 16 + fr;
        const int col = n0 + wn + ci;
        const f32x4 other = *(const f32x4*)(mrg + wq * 4352 + ci * 68 + ri);
        const float bia = bias[col];
#pragma unroll
        for (int j = 0; j < 4; ++j) {
          size_t idx = (size_t)(row0 + j) * 1024 + col;
          dst[idx] = acc[i][n][j] + other[j] + bia + resid[idx];
        }
      }
    }
  }
}

// ---------- flash attention: 32x32 MFMA, in-register P, KV-split-2, fast exp2 ----------
__global__ __launch_bounds__(512, 4) void attn_fwd(const u16* __restrict__ q,
                                                   const u16* __restrict__ k,
                                                   const u16* __restrict__ vt,
                                                   u16* __restrict__ ctx) {
  __shared__ __align__(16) u16 Ks[2][2][64 * 64];  // [half][buf]
  __shared__ __align__(16) u16 Vs[2][2][64 * 64];
  __shared__ float Lr[4][32];
  const int t = threadIdx.x, lane = t & 63, w = t >> 6;  // 8 waves
  const int qsub = w & 3, half = w >> 2;
  const int ql = lane & 31;
  const int h = lane >> 5;
  const int bid = blockIdx.x;
  const int bh = (bid & 7) * 4 + ((bid >> 3) & 3);  // 4 heads per XCD
  const int qt = bid >> 5;                          // 0..15
  const int q0w = qt * 128 + qsub * 32;
  const size_t hbase = (size_t)bh << 17;
  const u16* kg = k + hbase;
  const u16* vg = vt + hbase;
  const int srow = t >> 3;  // 0..63
  const int sl = t & 7;
  const int l7 = lane & 7;

  short8 qf[4];
#pragma unroll
  for (int f = 0; f < 4; ++f)
    qf[f] = *(const short8*)(q + hbase + (size_t)(q0w + ql) * 64 + f * 16 + h * 8);

  float la[4] = {0.f, 0.f, 0.f, 0.f};
  f32x16 o[2];
#pragma unroll
  for (int db = 0; db < 2; ++db)
#pragma unroll
    for (int r = 0; r < 16; ++r) o[db][r] = 0.f;

  auto stage = [&](int buf, int it1) {
    const int kt0 = it1 << 6;          // half 0
    const int kt1 = (16 + it1) << 6;   // half 1
    const int gs = sl ^ (srow & 7);
    gload16(kg + (size_t)(kt0 + srow) * 64 + gs * 8, &Ks[0][buf][srow * 64 + sl * 8]);
    gload16(kg + (size_t)(kt1 + srow) * 64 + gs * 8, &Ks[1][buf][srow * 64 + sl * 8]);
    gload16(vg + (size_t)srow * 2048 + kt0 + gs * 8, &Vs[0][buf][srow * 64 + sl * 8]);
    gload16(vg + (size_t)srow * 2048 + kt1 + gs * 8, &Vs[1][buf][srow * 64 + sl * 8]);
  };

  stage(0, 0);
  int buf = 0;
  for (int it = 0; it < 16; ++it) {
    VM0;
    BARR;
    if (it < 15) stage(buf ^ 1, it + 1);

    f32x16 s[2];
    PRIO1;
#pragma unroll
    for (int kb = 0; kb < 2; ++kb) {
#pragma unroll
      for (int r = 0; r < 16; ++r) s[kb][r] = 0.f;
#pragma unroll
      for (int f = 0; f < 4; ++f) {
        const u16* kr = &Ks[half][buf][(kb * 32 + ql) * 64 + (((2 * f + h) ^ l7) << 3)];
        s[kb] = __builtin_amdgcn_mfma_f32_32x32x16_bf16(*(const short8*)kr, qf[f],
                                                        s[kb], 0, 0, 0);
      }
    }
    PRIO0;

    float p[2][16];
#pragma unroll
    for (int kb = 0; kb < 2; ++kb)
#pragma unroll
      for (int r = 0; r < 16; ++r) {
        p[kb][r] = exp2_fast(s[kb][r]);
        la[r & 3] += p[kb][r];
      }

    short8 pf[4];
#pragma unroll
    for (int kb = 0; kb < 2; ++kb)
#pragma unroll
      for (int rrp = 0; rrp < 2; ++rrp) {
        u32 y0, y1, x0, x1;
        asm volatile("v_cvt_pk_bf16_f32 %0, %1, %2" : "=v"(y0)
                     : "v"(p[kb][8 * rrp + 0]), "v"(p[kb][8 * rrp + 1]));
        asm volatile("v_cvt_pk_bf16_f32 %0, %1, %2" : "=v"(y1)
                     : "v"(p[kb][8 * rrp + 2]), "v"(p[kb][8 * rrp + 3]));
        asm volatile("v_cvt_pk_bf16_f32 %0, %1, %2" : "=v"(x0)
                     : "v"(p[kb][8 * rrp + 4]), "v"(p[kb][8 * rrp + 5]));
        asm volatile("v_cvt_pk_bf16_f32 %0, %1, %2" : "=v"(x1)
                     : "v"(p[kb][8 * rrp + 6]), "v"(p[kb][8 * rrp + 7]));
        i32x2 r0 = __builtin_amdgcn_permlane32_swap((int)x0, (int)y0, false, false);
        i32x2 r1 = __builtin_amdgcn_permlane32_swap((int)x1, (int)y1, false, false);
        u32 dw[4] = {(u32)r0[1], (u32)r1[1], (u32)r0[0], (u32)r1[0]};
        pf[kb * 2 + rrp] = *(short8*)dw;
      }

    PRIO1;
#pragma unroll
    for (int db = 0; db < 2; ++db) {
#pragma unroll
      for (int f = 0; f < 4; ++f) {
        const u16* vr = &Vs[half][buf][(db * 32 + ql) * 64 + (((2 * f + h) ^ l7) << 3)];
        o[db] = __builtin_amdgcn_mfma_f32_32x32x16_bf16(pf[f], *(const short8*)vr,
                                                        o[db], 0, 0, 0);
      }
    }
    PRIO0;
    buf ^= 1;
  }

  float lacc = (la[0] + la[1]) + (la[2] + la[3]);
  lacc += __shfl_xor(lacc, 32, 64);

  BARR;  // all waves finished reading Ks/Vs
  float* mO = (float*)&Ks[0][0][0];
  float* mL = (float*)&Vs[0][0][0];
  if (half == 1) {
#pragma unroll
    for (int r = 0; r < 16; ++r) {
      const int qr = (r & 3) + 8 * (r >> 2) + 4 * h;
#pragma unroll
      for (int db = 0; db < 2; ++db)
        mO[(qsub * 32 + qr) * 64 + db * 32 + ql] = o[db][r];
    }
    if (h == 0) mL[qsub * 32 + ql] = lacc;
  }
  LGKM0;
  BARR;
  if (half == 0) {
    float lsum = lacc + mL[qsub * 32 + ql];
    Lr[qsub][ql] = 1.0f / lsum;
#pragma unroll
    for (int r = 0; r < 16; ++r) {
      const int qr = (r & 3) + 8 * (r >> 2) + 4 * h;
#pragma unroll
      for (int db = 0; db < 2; ++db)
        o[db][r] += mO[(qsub * 32 + qr) * 64 + db * 32 + ql];
    }
    LGKM0;
    const int bb = bh >> 4, hh = bh & 15;
#pragma unroll
    for (int r = 0; r < 16; ++r) {
      const int qr = (r & 3) + 8 * (r >> 2) + 4 * h;
      const float rl = Lr[qsub][qr];
      const int row = q0w + qr;
      const size_t base = (((size_t)(bb * 2048 + row)) << 10) + hh * 64;
#pragma unroll
      for (int db = 0; db < 2; ++db)
        ctx[base + db * 32 + ql] = f2bf(o[db][r] * rl);
    }
  }
}

extern "C" void kernel_launch(void* const* d_in, const int* in_sizes, int n_in,
                              void* d_out, int out_size, void* d_ws, size_t ws_size,
                              hipStream_t stream) {
  const float* x    = (const float*)d_in[0];
  const float* Wq   = (const float*)d_in[1];
  const float* bq   = (const float*)d_in[2];
  const float* Wk   = (const float*)d_in[3];
  const float* bk   = (const float*)d_in[4];
  const float* Wv   = (const float*)d_in[5];
  const float* bv   = (const float*)d_in[6];
  const float* Wo   = (const float*)d_in[7];
  const float* bo   = (const float*)d_in[8];
  const float* ln1g = (const float*)d_in[9];
  const float* ln1b = (const float*)d_in[10];
  const float* W1   = (const float*)d_in[11];
  const float* b1   = (const float*)d_in[12];
  const float* W2   = (const float*)d_in[13];
  const float* b2   = (const float*)d_in[14];
  const float* ln2g = (const float*)d_in[15];
  const float* ln2b = (const float*)d_in[16];

  char* ws = (char*)d_ws;
  size_t off = 0;
  auto alloc = [&](size_t bytes) {
    char* p = ws + off;
    off += (bytes + 1023) & ~(size_t)1023;
    return p;
  };
  u16* WQKVT = (u16*)alloc((size_t)3 * DM * DM * 2);  // [3072][1024]
  u16* WOT = (u16*)alloc((size_t)DM * DM * 2);
  u16* W1T = (u16*)alloc((size_t)DFF * DM * 2);  // [4096][1024]
  u16* W2T = (u16*)alloc((size_t)DM * DFF * 2);  // [1024][4096]
  float* COS = (float*)alloc((size_t)S_LEN * 32 * 4);
  float* SIN = (float*)alloc((size_t)S_LEN * 32 * 4);
  u16* H   = (u16*)alloc((size_t)MTOK * DM * 2);   // h1, later h2
  u16* Qb  = (u16*)alloc((size_t)MTOK * DM * 2);   // [bh][s][64]
  u16* Kb  = (u16*)alloc((size_t)MTOK * DM * 2);
  u16* VT  = (u16*)alloc((size_t)MTOK * DM * 2);   // [bh][64][s]
  u16* CTX = (u16*)alloc((size_t)MTOK * DM * 2);
  float* X2 = (float*)alloc((size_t)MTOK * DM * 4);
  u16* FFN1 = Qb;  // reuse Qb..CTX after attention
  if (ws_size < off) return;

  dim3 blk256(256);
  // fused prep: 6 transposes + rope table + LN1  (16640 blocks)
  prep<<<dim3(16640), blk256, 0, stream>>>(Wq, Wk, Wv, Wo, W1, W2, WQKVT, WOT,
                                           W1T, W2T, COS, SIN, x, ln1g, ln1b, H);
  // fused QKV (m201-style 256² pipeline) + bias + RoPE + V transpose
  gemm256<0><<<dim3(12, 16), dim3(512), 0, stream>>>(
      H, WQKVT, 3072, 1024, nullptr, bq, bk, bv, COS, SIN, Qb, Kb, VT);
  // attention (32x32 MFMA, in-register P, kv-split-2, fast exp2)
  attn_fwd<<<dim3(512), dim3(512), 0, stream>>>(Qb, Kb, VT, CTX);
  // Wo + residual -> X2 (fp32)
  gemm_split<<<dim3(256), dim3(512), 0, stream>>>(CTX, WOT, 1024, bo, x, X2);
  // LN2
  ln_bf16<<<4096, blk256, 0, stream>>>(X2, ln2g, ln2b, H);
  // FFN1 + GELU (m201-style 256² pipeline)
  gemm256<1><<<dim3(16, 16), dim3(512), 0, stream>>>(
      H, W1T, 4096, 1024, b1, nullptr, nullptr, nullptr, nullptr, nullptr,
      FFN1, nullptr, nullptr);
  // FFN2 + residual -> out (fp32)
  gemm_split<<<dim3(256), dim3(512), 0, stream>>>(FFN1, W2T, 4096, b2, X2, (float*)d_out);
}

// Round 17
// 216.074 us; speedup vs baseline: 1.0350x; 1.0350x over previous
//
#include <hip/hip_runtime.h>
#include <hip/hip_bf16.h>
#include <stdint.h>

#define S_LEN 2048
#define NH 16
#define HD 64
#define DM 1024
#define DFF 4096
#define MTOK 4096   // B*S = 2*2048

typedef __attribute__((ext_vector_type(8))) short short8;
typedef __attribute__((ext_vector_type(4))) float f32x4;
typedef __attribute__((ext_vector_type(16))) float f32x16;
typedef __attribute__((ext_vector_type(2))) int i32x2;
typedef unsigned short u16;
typedef unsigned int u32;

__device__ __forceinline__ float bf2f(u16 u) {
  union { u32 i; float f; } x; x.i = ((u32)u) << 16; return x.f;
}
__device__ __forceinline__ u16 f2bf(float f) {
  union { float f; u32 i; } x; x.f = f;
  u32 r = x.i + 0x7fffu + ((x.i >> 16) & 1u);
  return (u16)(r >> 16);
}
// Schraudolph fast exp2 (full-rate fma+cvt; softmax normalization cancels bias)
__device__ __forceinline__ float exp2_fast(float x) {
  union { int i; float f; } u;
  u.i = (int)__builtin_fmaf(x, 8388608.0f, 1064986823.0f);
  return u.f;
}
__device__ __forceinline__ void gload16(const u16* g, u16* l) {
  __builtin_amdgcn_global_load_lds(
      (__attribute__((address_space(1))) u32*)g,
      (__attribute__((address_space(3))) u32*)l, 16, 0, 0);
}

#define VM0 asm volatile("s_waitcnt vmcnt(0)" ::: "memory")
#define BARR do { __builtin_amdgcn_s_barrier(); asm volatile("" ::: "memory"); } while (0)
#define LGKM0 do { asm volatile("s_waitcnt lgkmcnt(0)" ::: "memory"); __builtin_amdgcn_sched_barrier(0); } while (0)
#define PRIO1 __builtin_amdgcn_s_setprio(1)
#define PRIO0 __builtin_amdgcn_s_setprio(0)

// ---------- fused prep: 6 weight transposes + RoPE table + LN1, one launch ----------
__device__ __forceinline__ void transpose_tile(const float* __restrict__ W,
                                               u16* __restrict__ Wt, int K, int N,
                                               int n0, int k0, int tx, int ty,
                                               float (*tile)[33]) {
#pragma unroll
  for (int i = 0; i < 4; ++i)
    tile[ty + i * 8][tx] = W[(size_t)(k0 + ty + i * 8) * N + n0 + tx];
  __syncthreads();
#pragma unroll
  for (int i = 0; i < 4; ++i)
    Wt[(size_t)(n0 + ty + i * 8) * K + k0 + tx] = f2bf(tile[tx][ty + i * 8]);
}

__global__ __launch_bounds__(256) void prep(
    const float* __restrict__ Wq, const float* __restrict__ Wk,
    const float* __restrict__ Wv, const float* __restrict__ Wo,
    const float* __restrict__ W1, const float* __restrict__ W2,
    u16* __restrict__ WQKVT, u16* __restrict__ WOT, u16* __restrict__ W1T,
    u16* __restrict__ W2T, float* __restrict__ cosT, float* __restrict__ sinT,
    const float* __restrict__ x, const float* __restrict__ g,
    const float* __restrict__ b, u16* __restrict__ H) {
  __shared__ float tile[32][33];
  __shared__ float red[8];
  const int r = blockIdx.x;
  const int t = threadIdx.x;
  const int tx = t & 31, ty = t >> 5;
  if (r < 4096) {
    const float* W = (r < 1024) ? Wq : (r < 2048) ? Wk : (r < 3072) ? Wv : Wo;
    u16* Wt = (r < 1024) ? WQKVT
              : (r < 2048) ? WQKVT + 1024 * 1024
              : (r < 3072) ? WQKVT + 2 * 1024 * 1024 : WOT;
    int sub = r & 1023;
    transpose_tile(W, Wt, 1024, 1024, (sub & 31) * 32, (sub >> 5) * 32, tx, ty, tile);
  } else if (r < 8192) {
    int sub = r - 4096;  // W1: K=1024, N=4096
    transpose_tile(W1, W1T, 1024, 4096, (sub & 127) * 32, (sub >> 7) * 32, tx, ty, tile);
  } else if (r < 12288) {
    int sub = r - 8192;  // W2: K=4096, N=1024
    transpose_tile(W2, W2T, 4096, 1024, (sub & 31) * 32, (sub >> 5) * 32, tx, ty, tile);
  } else if (r < 12544) {
    int id = (r - 12288) * 256 + t;  // 2048*32
    int s = id >> 5, j = id & 31;
    float inv = powf(10000.0f, -(float)j * (1.0f / 32.0f));
    float fr = (float)s * inv;
    cosT[id] = cosf(fr);
    sinT[id] = sinf(fr);
  } else {
    // LN1 row
    int row = r - 12544;
    float4 v = ((const float4*)(x + ((size_t)row << 10)))[t];
    float s = v.x + v.y + v.z + v.w;
    float q = v.x * v.x + v.y * v.y + v.z * v.z + v.w * v.w;
#pragma unroll
    for (int m = 1; m < 64; m <<= 1) {
      s += __shfl_xor(s, m, 64);
      q += __shfl_xor(q, m, 64);
    }
    int lane = t & 63, w = t >> 6;
    if (lane == 0) { red[w] = s; red[4 + w] = q; }
    __syncthreads();
    s = red[0] + red[1] + red[2] + red[3];
    q = red[4] + red[5] + red[6] + red[7];
    float mu = s * (1.0f / 1024.0f);
    float var = q * (1.0f / 1024.0f) - mu * mu;
    float rstd = rsqrtf(var + 1e-5f);
    float4 gv = ((const float4*)g)[t];
    float4 bv = ((const float4*)b)[t];
    ushort4 o;
    o.x = f2bf((v.x - mu) * rstd * gv.x + bv.x);
    o.y = f2bf((v.y - mu) * rstd * gv.y + bv.y);
    o.z = f2bf((v.z - mu) * rstd * gv.z + bv.z);
    o.w = f2bf((v.w - mu) * rstd * gv.w + bv.w);
    ((ushort4*)(H + ((size_t)row << 10)))[t] = o;
  }
}

// ---------- LayerNorm fp32 row(1024) -> bf16 (LN2) ----------
__global__ __launch_bounds__(256) void ln_bf16(const float* __restrict__ x,
                                               const float* __restrict__ g,
                                               const float* __restrict__ b,
                                               u16* __restrict__ out) {
  int row = blockIdx.x;
  int t = threadIdx.x;
  float4 v = ((const float4*)(x + ((size_t)row << 10)))[t];
  float s = v.x + v.y + v.z + v.w;
  float q = v.x * v.x + v.y * v.y + v.z * v.z + v.w * v.w;
#pragma unroll
  for (int m = 1; m < 64; m <<= 1) {
    s += __shfl_xor(s, m, 64);
    q += __shfl_xor(q, m, 64);
  }
  __shared__ float red[8];
  int lane = t & 63, w = t >> 6;
  if (lane == 0) { red[w] = s; red[4 + w] = q; }
  __syncthreads();
  s = red[0] + red[1] + red[2] + red[3];
  q = red[4] + red[5] + red[6] + red[7];
  float mu = s * (1.0f / 1024.0f);
  float var = q * (1.0f / 1024.0f) - mu * mu;
  float rstd = rsqrtf(var + 1e-5f);
  float4 gv = ((const float4*)g)[t];
  float4 bv = ((const float4*)b)[t];
  ushort4 o;
  o.x = f2bf((v.x - mu) * rstd * gv.x + bv.x);
  o.y = f2bf((v.y - mu) * rstd * gv.y + bv.y);
  o.z = f2bf((v.z - mu) * rstd * gv.z + bv.z);
  o.w = f2bf((v.w - mu) * rstd * gv.w + bv.w);
  ((ushort4*)(out + ((size_t)row << 10)))[t] = o;
}

// ---------- m97-classic 128x128 GEMM: 32KB LDS, 3 blocks/CU, XOR-swizzled ----------
// 256 thr / 4 waves (64x64 wave tiles, 0.5 b128-reads per MFMA). Two barriers per
// K-step; inter-block overlap (3/CU) hides the vmcnt drain. XCD-chunked grid.
// EPI 0: QKV epilogue (bias + RoPE + Q*(0.125*log2e) + V transpose)
// EPI 1: gelu(acc + bias) -> bf16 [M][N]
template <int EPI>
__global__ __launch_bounds__(256, 3) void gemm128(
    const u16* __restrict__ A, const u16* __restrict__ Bt, int N, int K,
    const float* __restrict__ bias, const float* __restrict__ bq,
    const float* __restrict__ bk, const float* __restrict__ bv,
    const float* __restrict__ cosT, const float* __restrict__ sinT,
    u16* __restrict__ d0, u16* __restrict__ d1, u16* __restrict__ d2) {
  __shared__ __align__(16) u16 As[128 * 64];
  __shared__ __align__(16) u16 Bs[128 * 64];
  const int t = threadIdx.x;
  const int lane = t & 63, wid = t >> 6;
  const int fr = lane & 15, fq = lane >> 4;
  const int r7 = fr & 7;
  const int bid = blockIdx.x;
  // XCD-chunked: xcd owns 4 consecutive m-tiles x all n-tiles
  const int mt = (bid & 7) * 4 + ((bid >> 3) & 3);
  const int ntl = bid >> 5;
  const int m0 = mt << 7, n0 = ntl << 7;
  const int wm = (wid >> 1) << 6, wn = (wid & 1) << 6;
  const int srow = t >> 3, ssl = t & 7;

  f32x4 acc[4][4];
#pragma unroll
  for (int i = 0; i < 4; ++i)
#pragma unroll
    for (int n = 0; n < 4; ++n) acc[i][n] = (f32x4){0.f, 0.f, 0.f, 0.f};

  for (int kt = 0; kt < K; kt += 64) {
    __syncthreads();  // previous compute done before overwrite
#pragma unroll
    for (int c = 0; c < 4; ++c) {
      const int R = (c << 5) + srow;
      const int gs = ssl ^ (R & 7);
      gload16(A + (size_t)(m0 + R) * K + kt + gs * 8, As + R * 64 + ssl * 8);
      gload16(Bt + (size_t)(n0 + R) * K + kt + gs * 8, Bs + R * 64 + ssl * 8);
    }
    __syncthreads();  // implicit vmcnt(0) drain; hidden by other blocks (3/CU)
    short8 a[4][2], b[4][2];
#pragma unroll
    for (int i = 0; i < 4; ++i) {
      const u16* rp = &As[(wm + i * 16 + fr) * 64];
#pragma unroll
      for (int ks = 0; ks < 2; ++ks)
        a[i][ks] = *(const short8*)(rp + (((ks * 4 + fq) ^ r7) << 3));
    }
#pragma unroll
    for (int n = 0; n < 4; ++n) {
      const u16* rp = &Bs[(wn + n * 16 + fr) * 64];
#pragma unroll
      for (int ks = 0; ks < 2; ++ks)
        b[n][ks] = *(const short8*)(rp + (((ks * 4 + fq) ^ r7) << 3));
    }
    PRIO1;
#pragma unroll
    for (int i = 0; i < 4; ++i)
#pragma unroll
      for (int n = 0; n < 4; ++n)
#pragma unroll
        for (int ks = 0; ks < 2; ++ks)
          acc[i][n] = __builtin_amdgcn_mfma_f32_16x16x32_bf16(a[i][ks], b[n][ks],
                                                              acc[i][n], 0, 0, 0);
    PRIO0;
  }

  if (EPI == 0) {
    const int colbase = n0 + wn;        // 64-aligned; wave spans one head
    const int slice = colbase >> 10;    // 0=Q 1=K 2=V
    const int cb = colbase & 1023;
    const int hh = cb >> 6;
    if (slice < 2) {
      const float sc = (slice == 0) ? 0.125f * 1.44269504088896f : 1.0f;
      const float* bb_ = (slice == 0) ? bq : bk;
      u16* dst = (slice == 0) ? d0 : d1;
#pragma unroll
      for (int i = 0; i < 4; ++i) {
        const int row0 = m0 + wm + i * 16 + (fq << 2);
#pragma unroll
        for (int n = 0; n < 2; ++n) {
          const int d = n * 16 + fr;
          const float blo = bb_[cb + d];
          const float bhi = bb_[cb + d + 32];
#pragma unroll
          for (int j = 0; j < 4; ++j) {
            const int row = row0 + j;
            const int ss = row & 2047, bb2 = row >> 11;
            const float c = cosT[ss * 32 + d];
            const float sn = sinT[ss * 32 + d];
            const float av = acc[i][n][j] + blo;
            const float bv2 = acc[i][n + 2][j] + bhi;
            const size_t base = ((size_t)((bb2 * 16 + hh) * 2048 + ss)) << 6;
            dst[base + d] = f2bf((av * c - bv2 * sn) * sc);
            dst[base + d + 32] = f2bf((bv2 * c + av * sn) * sc);
          }
        }
      }
    } else {
#pragma unroll
      for (int i = 0; i < 4; ++i) {
        const int row0 = m0 + wm + i * 16 + (fq << 2);
#pragma unroll
        for (int n = 0; n < 4; ++n) {
          const int d = n * 16 + fr;
          const float bia = bv[cb + d];
#pragma unroll
          for (int j = 0; j < 4; ++j) {
            const int row = row0 + j;
            const int ss = row & 2047, bb2 = row >> 11;
            d2[((size_t)((bb2 * 16 + hh) * 64 + d)) * 2048 + ss] =
                f2bf(acc[i][n][j] + bia);
          }
        }
      }
    }
  } else {
#pragma unroll
    for (int i = 0; i < 4; ++i) {
      const int row0 = m0 + wm + i * 16 + (fq << 2);
#pragma unroll
      for (int n = 0; n < 4; ++n) {
        const int col = n0 + wn + n * 16 + fr;
        const float bia = bias[col];
#pragma unroll
        for (int j = 0; j < 4; ++j) {
          const int row = row0 + j;
          const float v = acc[i][n][j] + bia;
          const float gl = 0.5f * v * (1.0f + erff(v * 0.70710678118f));
          d0[(size_t)row * N + col] = f2bf(gl);
        }
      }
    }
  }
}

// ---------- N=1024 GEMM (Wo, FFN2): 128x128 tile, intra-block split-K ----------
__global__ __launch_bounds__(512, 1) void gemm_split(
    const u16* __restrict__ A, const u16* __restrict__ Bt, int K,
    const float* __restrict__ bias, const float* __restrict__ resid,
    float* __restrict__ dst) {
  __shared__ __align__(16) u16 As[2][128 * 128];
  __shared__ __align__(16) u16 Bs[2][128 * 128];
  const int t = threadIdx.x, lane = t & 63, w = t >> 6;  // 8 waves
  const int fr = lane & 15, fq = lane >> 4;
  const int wq = w & 3, kh = w >> 2;
  const int wm = (wq >> 1) << 6, wn = (wq & 1) << 6;
  const int bid = blockIdx.x;
  const int xcd = bid & 7, within = bid >> 3;            // 32 blocks/XCD
  const int m0 = (xcd * 4 + (within >> 3)) << 7;         // 32 m-tiles
  const int n0 = (within & 7) << 7;                      // 8 n-tiles
  const int srow = t >> 4;   // 0..31
  const int ssl = t & 15;    // 16B slot 0..15

  f32x4 acc[4][4];
#pragma unroll
  for (int i = 0; i < 4; ++i)
#pragma unroll
    for (int n = 0; n < 4; ++n) acc[i][n] = (f32x4){0.f, 0.f, 0.f, 0.f};

  auto stage = [&](int buf, int kt) {
#pragma unroll
    for (int c = 0; c < 4; ++c) {
      const int R = c * 32 + srow;
      const int gs = ssl ^ (R & 15);
      gload16(A + (size_t)(m0 + R) * K + kt + gs * 8, &As[buf][R * 128 + ssl * 8]);
    }
#pragma unroll
    for (int c = 0; c < 4; ++c) {
      const int R = c * 32 + srow;
      const int gs = ssl ^ (R & 15);
      gload16(Bt + (size_t)(n0 + R) * K + kt + gs * 8, &Bs[buf][R * 128 + ssl * 8]);
    }
  };

  stage(0, 0);
  int buf = 0;
  const int iters = K >> 7;
  for (int it = 0; it < iters; ++it) {
    VM0;
    BARR;
    if (it + 1 < iters) stage(buf ^ 1, (it + 1) << 7);

    short8 a[4][2], b[4][2];
#pragma unroll
    for (int i = 0; i < 4; ++i) {
      const u16* rp = &As[buf][(wm + i * 16 + fr) * 128];
#pragma unroll
      for (int ks = 0; ks < 2; ++ks)
        a[i][ks] = *(const short8*)(rp + (((kh * 8 + ks * 4 + fq) ^ fr) << 3));
    }
#pragma unroll
    for (int n = 0; n < 4; ++n) {
      const u16* rp = &Bs[buf][(wn + n * 16 + fr) * 128];
#pragma unroll
      for (int ks = 0; ks < 2; ++ks)
        b[n][ks] = *(const short8*)(rp + (((kh * 8 + ks * 4 + fq) ^ fr) << 3));
    }
    PRIO1;
#pragma unroll
    for (int i = 0; i < 4; ++i)
#pragma unroll
      for (int n = 0; n < 4; ++n)
#pragma unroll
        for (int ks = 0; ks < 2; ++ks)
          acc[i][n] = __builtin_amdgcn_mfma_f32_16x16x32_bf16(a[i][ks], b[n][ks],
                                                              acc[i][n], 0, 0, 0);
    PRIO0;
    buf ^= 1;
  }

  // ---- k-half merge via LDS: [wq][col 0..63][row 0..63 pad->68] f32
  BARR;
  float* mrg = (float*)&As[0][0];
  if (kh == 1) {
#pragma unroll
    for (int i = 0; i < 4; ++i) {
      const int ri = i * 16 + (fq << 2);
#pragma unroll
      for (int n = 0; n < 4; ++n) {
        const int ci = n * 16 + fr;
        *(f32x4*)(mrg + wq * 4352 + ci * 68 + ri) = acc[i][n];
      }
    }
  }
  LGKM0;
  BARR;
  if (kh == 0) {
#pragma unroll
    for (int i = 0; i < 4; ++i) {
      const int ri = i * 16 + (fq << 2);
      const int row0 = m0 + wm + ri;
#pragma unroll
      for (int n = 0; n < 4; ++n) {
        const int ci = n * 16 + fr;
        const int col = n0 + wn + ci;
        const f32x4 other = *(const f32x4*)(mrg + wq * 4352 + ci * 68 + ri);
        const float bia = bias[col];
#pragma unroll
        for (int j = 0; j < 4; ++j) {
          size_t idx = (size_t)(row0 + j) * 1024 + col;
          dst[idx] = acc[i][n][j] + other[j] + bia + resid[idx];
        }
      }
    }
  }
}

// ---------- flash attention: 32x32 MFMA, in-register P, KV-split-2, fast exp2 ----------
__global__ __launch_bounds__(512, 4) void attn_fwd(const u16* __restrict__ q,
                                                   const u16* __restrict__ k,
                                                   const u16* __restrict__ vt,
                                                   u16* __restrict__ ctx) {
  __shared__ __align__(16) u16 Ks[2][2][64 * 64];  // [half][buf]
  __shared__ __align__(16) u16 Vs[2][2][64 * 64];
  __shared__ float Lr[4][32];
  const int t = threadIdx.x, lane = t & 63, w = t >> 6;  // 8 waves
  const int qsub = w & 3, half = w >> 2;
  const int ql = lane & 31;
  const int h = lane >> 5;
  const int bid = blockIdx.x;
  const int bh = (bid & 7) * 4 + ((bid >> 3) & 3);  // 4 heads per XCD
  const int qt = bid >> 5;                          // 0..15
  const int q0w = qt * 128 + qsub * 32;
  const size_t hbase = (size_t)bh << 17;
  const u16* kg = k + hbase;
  const u16* vg = vt + hbase;
  const int srow = t >> 3;  // 0..63
  const int sl = t & 7;
  const int l7 = lane & 7;

  short8 qf[4];
#pragma unroll
  for (int f = 0; f < 4; ++f)
    qf[f] = *(const short8*)(q + hbase + (size_t)(q0w + ql) * 64 + f * 16 + h * 8);

  float la[4] = {0.f, 0.f, 0.f, 0.f};
  f32x16 o[2];
#pragma unroll
  for (int db = 0; db < 2; ++db)
#pragma unroll
    for (int r = 0; r < 16; ++r) o[db][r] = 0.f;

  auto stage = [&](int buf, int it1) {
    const int kt0 = it1 << 6;          // half 0
    const int kt1 = (16 + it1) << 6;   // half 1
    const int gs = sl ^ (srow & 7);
    gload16(kg + (size_t)(kt0 + srow) * 64 + gs * 8, &Ks[0][buf][srow * 64 + sl * 8]);
    gload16(kg + (size_t)(kt1 + srow) * 64 + gs * 8, &Ks[1][buf][srow * 64 + sl * 8]);
    gload16(vg + (size_t)srow * 2048 + kt0 + gs * 8, &Vs[0][buf][srow * 64 + sl * 8]);
    gload16(vg + (size_t)srow * 2048 + kt1 + gs * 8, &Vs[1][buf][srow * 64 + sl * 8]);
  };

  stage(0, 0);
  int buf = 0;
  for (int it = 0; it < 16; ++it) {
    VM0;
    BARR;
    if (it < 15) stage(buf ^ 1, it + 1);

    f32x16 s[2];
    PRIO1;
#pragma unroll
    for (int kb = 0; kb < 2; ++kb) {
#pragma unroll
      for (int r = 0; r < 16; ++r) s[kb][r] = 0.f;
#pragma unroll
      for (int f = 0; f < 4; ++f) {
        const u16* kr = &Ks[half][buf][(kb * 32 + ql) * 64 + (((2 * f + h) ^ l7) << 3)];
        s[kb] = __builtin_amdgcn_mfma_f32_32x32x16_bf16(*(const short8*)kr, qf[f],
                                                        s[kb], 0, 0, 0);
      }
    }
    PRIO0;

    float p[2][16];
#pragma unroll
    for (int kb = 0; kb < 2; ++kb)
#pragma unroll
      for (int r = 0; r < 16; ++r) {
        p[kb][r] = exp2_fast(s[kb][r]);
        la[r & 3] += p[kb][r];
      }

    short8 pf[4];
#pragma unroll
    for (int kb = 0; kb < 2; ++kb)
#pragma unroll
      for (int rrp = 0; rrp < 2; ++rrp) {
        u32 y0, y1, x0, x1;
        asm volatile("v_cvt_pk_bf16_f32 %0, %1, %2" : "=v"(y0)
                     : "v"(p[kb][8 * rrp + 0]), "v"(p[kb][8 * rrp + 1]));
        asm volatile("v_cvt_pk_bf16_f32 %0, %1, %2" : "=v"(y1)
                     : "v"(p[kb][8 * rrp + 2]), "v"(p[kb][8 * rrp + 3]));
        asm volatile("v_cvt_pk_bf16_f32 %0, %1, %2" : "=v"(x0)
                     : "v"(p[kb][8 * rrp + 4]), "v"(p[kb][8 * rrp + 5]));
        asm volatile("v_cvt_pk_bf16_f32 %0, %1, %2" : "=v"(x1)
                     : "v"(p[kb][8 * rrp + 6]), "v"(p[kb][8 * rrp + 7]));
        i32x2 r0 = __builtin_amdgcn_permlane32_swap((int)x0, (int)y0, false, false);
        i32x2 r1 = __builtin_amdgcn_permlane32_swap((int)x1, (int)y1, false, false);
        u32 dw[4] = {(u32)r0[1], (u32)r1[1], (u32)r0[0], (u32)r1[0]};
        pf[kb * 2 + rrp] = *(short8*)dw;
      }

    PRIO1;
#pragma unroll
    for (int db = 0; db < 2; ++db) {
#pragma unroll
      for (int f = 0; f < 4; ++f) {
        const u16* vr = &Vs[half][buf][(db * 32 + ql) * 64 + (((2 * f + h) ^ l7) << 3)];
        o[db] = __builtin_amdgcn_mfma_f32_32x32x16_bf16(pf[f], *(const short8*)vr,
                                                        o[db], 0, 0, 0);
      }
    }
    PRIO0;
    buf ^= 1;
  }

  float lacc = (la[0] + la[1]) + (la[2] + la[3]);
  lacc += __shfl_xor(lacc, 32, 64);

  BARR;  // all waves finished reading Ks/Vs
  float* mO = (float*)&Ks[0][0][0];
  float* mL = (float*)&Vs[0][0][0];
  if (half == 1) {
#pragma unroll
    for (int r = 0; r < 16; ++r) {
      const int qr = (r & 3) + 8 * (r >> 2) + 4 * h;
#pragma unroll
      for (int db = 0; db < 2; ++db)
        mO[(qsub * 32 + qr) * 64 + db * 32 + ql] = o[db][r];
    }
    if (h == 0) mL[qsub * 32 + ql] = lacc;
  }
  LGKM0;
  BARR;
  if (half == 0) {
    float lsum = lacc + mL[qsub * 32 + ql];
    Lr[qsub][ql] = 1.0f / lsum;
#pragma unroll
    for (int r = 0; r < 16; ++r) {
      const int qr = (r & 3) + 8 * (r >> 2) + 4 * h;
#pragma unroll
      for (int db = 0; db < 2; ++db)
        o[db][r] += mO[(qsub * 32 + qr) * 64 + db * 32 + ql];
    }
    LGKM0;
    const int bb = bh >> 4, hh = bh & 15;
#pragma unroll
    for (int r = 0; r < 16; ++r) {
      const int qr = (r & 3) + 8 * (r >> 2) + 4 * h;
      const float rl = Lr[qsub][qr];
      const int row = q0w + qr;
      const size_t base = (((size_t)(bb * 2048 + row)) << 10) + hh * 64;
#pragma unroll
      for (int db = 0; db < 2; ++db)
        ctx[base + db * 32 + ql] = f2bf(o[db][r] * rl);
    }
  }
}

extern "C" void kernel_launch(void* const* d_in, const int* in_sizes, int n_in,
                              void* d_out, int out_size, void* d_ws, size_t ws_size,
                              hipStream_t stream) {
  const float* x    = (const float*)d_in[0];
  const float* Wq   = (const float*)d_in[1];
  const float* bq   = (const float*)d_in[2];
  const float* Wk   = (const float*)d_in[3];
  const float* bk   = (const float*)d_in[4];
  const float* Wv   = (const float*)d_in[5];
  const float* bv   = (const float*)d_in[6];
  const float* Wo   = (const float*)d_in[7];
  const float* bo   = (const float*)d_in[8];
  const float* ln1g = (const float*)d_in[9];
  const float* ln1b = (const float*)d_in[10];
  const float* W1   = (const float*)d_in[11];
  const float* b1   = (const float*)d_in[12];
  const float* W2   = (const float*)d_in[13];
  const float* b2   = (const float*)d_in[14];
  const float* ln2g = (const float*)d_in[15];
  const float* ln2b = (const float*)d_in[16];

  char* ws = (char*)d_ws;
  size_t off = 0;
  auto alloc = [&](size_t bytes) {
    char* p = ws + off;
    off += (bytes + 1023) & ~(size_t)1023;
    return p;
  };
  u16* WQKVT = (u16*)alloc((size_t)3 * DM * DM * 2);  // [3072][1024]
  u16* WOT = (u16*)alloc((size_t)DM * DM * 2);
  u16* W1T = (u16*)alloc((size_t)DFF * DM * 2);  // [4096][1024]
  u16* W2T = (u16*)alloc((size_t)DM * DFF * 2);  // [1024][4096]
  float* COS = (float*)alloc((size_t)S_LEN * 32 * 4);
  float* SIN = (float*)alloc((size_t)S_LEN * 32 * 4);
  u16* H   = (u16*)alloc((size_t)MTOK * DM * 2);   // h1, later h2
  u16* Qb  = (u16*)alloc((size_t)MTOK * DM * 2);   // [bh][s][64]
  u16* Kb  = (u16*)alloc((size_t)MTOK * DM * 2);
  u16* VT  = (u16*)alloc((size_t)MTOK * DM * 2);   // [bh][64][s]
  u16* CTX = (u16*)alloc((size_t)MTOK * DM * 2);
  float* X2 = (float*)alloc((size_t)MTOK * DM * 4);
  u16* FFN1 = Qb;  // reuse Qb..CTX after attention
  if (ws_size < off) return;

  dim3 blk256(256);
  // fused prep: 6 transposes + rope table + LN1  (16640 blocks)
  prep<<<dim3(16640), blk256, 0, stream>>>(Wq, Wk, Wv, Wo, W1, W2, WQKVT, WOT,
                                           W1T, W2T, COS, SIN, x, ln1g, ln1b, H);
  // fused QKV (m97-classic 128², 3 blocks/CU) + bias + RoPE + V transpose
  gemm128<0><<<dim3(768), blk256, 0, stream>>>(
      H, WQKVT, 3072, 1024, nullptr, bq, bk, bv, COS, SIN, Qb, Kb, VT);
  // attention (32x32 MFMA, in-register P, kv-split-2, fast exp2)
  attn_fwd<<<dim3(512), dim3(512), 0, stream>>>(Qb, Kb, VT, CTX);
  // Wo + residual -> X2 (fp32)
  gemm_split<<<dim3(256), dim3(512), 0, stream>>>(CTX, WOT, 1024, bo, x, X2);
  // LN2
  ln_bf16<<<4096, blk256, 0, stream>>>(X2, ln2g, ln2b, H);
  // FFN1 + GELU (m97-classic 128²)
  gemm128<1><<<dim3(1024), blk256, 0, stream>>>(
      H, W1T, 4096, 1024, b1, nullptr, nullptr, nullptr, nullptr, nullptr,
      FFN1, nullptr, nullptr);
  // FFN2 + residual -> out (fp32)
  gemm_split<<<dim3(256), dim3(512), 0, stream>>>(FFN1, W2T, 4096, b2, X2, (float*)d_out);
}